// Round 1
// baseline (1023.647 us; speedup 1.0000x reference)
//
#include <hip/hip_runtime.h>
#include <math.h>

#define N 4096
#define D 128
#define FEPS 1e-5f
#define C0F 0.993262053f

typedef __attribute__((ext_vector_type(8))) short bf16x8;
typedef __attribute__((ext_vector_type(4))) float f32x4;

__device__ __forceinline__ unsigned short f2bf(float f) {
    union { float f; unsigned u; } v; v.f = f;
    unsigned r = v.u + 0x7fffu + ((v.u >> 16) & 1u);
    return (unsigned short)(r >> 16);
}
__device__ __forceinline__ float bf2f(short s) {
    union { unsigned u; float f; } v; v.u = ((unsigned)(unsigned short)s) << 16;
    return v.f;
}

__device__ __forceinline__ void async16(void* lds, const void* g) {
    __builtin_amdgcn_global_load_lds(
        (const __attribute__((address_space(1))) unsigned int*)g,
        (__attribute__((address_space(3))) unsigned int*)lds, 16, 0, 0);
}

// ---------------- reduction helpers ----------------
__device__ __forceinline__ double block_reduce256(double v, double* red) {
    int t = threadIdx.x;
    red[t] = v;
    __syncthreads();
    #pragma unroll
    for (int s = 128; s > 0; s >>= 1) {
        if (t < s) red[t] += red[t + s];
        __syncthreads();
    }
    double r = red[0];
    __syncthreads();
    return r;
}

// ---------------- gather + row norms ----------------
__global__ void gather_energy(const float* __restrict__ W, const int* __restrict__ idx,
                              float* __restrict__ E, float* __restrict__ energy) {
    int i = blockIdx.x, t = threadIdx.x;
    float v = W[(size_t)idx[i] * D + t];
    E[(size_t)i * D + t] = v;
    float sq = v * v;
    #pragma unroll
    for (int o = 32; o > 0; o >>= 1) sq += __shfl_down(sq, o);
    __shared__ float s2[2];
    if ((t & 63) == 0) s2[t >> 6] = sq;
    __syncthreads();
    if (t == 0) energy[i] = sqrtf(s2[0] + s2[1]);
}

// ---------------- trans -> bf16 A-fmt (Ta) + B-fmt (Tb), FUSED row/col sums --
// A-fmt slot(r,c) = ((r>>4)*(N/8) + (c>>3))*128 + (r&15)*8 + (c&7), holds M[r][c]
// B-fmt slot for (k,n) = A-fmt slot(n,k), holds M[k][n]
// Also: trow[i] += row sums, tcol[j] += col sums, sc[5] += total (one 64MB pass
// instead of three).  trow/tcol must be zeroed.
__global__ void trans_convert(const float* __restrict__ T,
                              unsigned short* __restrict__ Ta,
                              unsigned short* __restrict__ Tb,
                              float* __restrict__ trow, float* __restrict__ tcol,
                              double* __restrict__ sc) {
    __shared__ float cs[4][256];
    __shared__ float ws[4];
    int t = threadIdx.x;
    int cb = blockIdx.x * 64 + (t & 63);   // col-block (4 cols)
    int rb = blockIdx.y * 4 + (t >> 6);    // row-block (4 rows)
    int r0 = rb * 4, c0 = cb * 4;
    float vv[4][4];
    #pragma unroll
    for (int i = 0; i < 4; ++i) {
        float4 r4 = *(const float4*)&T[(size_t)(r0 + i) * N + c0];
        vv[i][0] = r4.x; vv[i][1] = r4.y; vv[i][2] = r4.z; vv[i][3] = r4.w;
    }
    #pragma unroll
    for (int i = 0; i < 4; ++i) {
        int r = r0 + i;
        size_t slot = ((size_t)(r >> 4) * (N / 8) + (c0 >> 3)) * 128 + (r & 15) * 8 + (c0 & 7);
        short4 s;
        s.x = (short)f2bf(vv[i][0]); s.y = (short)f2bf(vv[i][1]);
        s.z = (short)f2bf(vv[i][2]); s.w = (short)f2bf(vv[i][3]);
        *(short4*)&Ta[slot] = s;
    }
    #pragma unroll
    for (int j = 0; j < 4; ++j) {
        int n = c0 + j;
        size_t slot = ((size_t)(n >> 4) * (N / 8) + (r0 >> 3)) * 128 + (n & 15) * 8 + (r0 & 7);
        short4 s;
        s.x = (short)f2bf(vv[0][j]); s.y = (short)f2bf(vv[1][j]);
        s.z = (short)f2bf(vv[2][j]); s.w = (short)f2bf(vv[3][j]);
        *(short4*)&Tb[slot] = s;
    }
    // ---- row sums: the 64 lanes of a wave all own the same 4 rows ----
    float wtot = 0.f;
    #pragma unroll
    for (int i = 0; i < 4; ++i) {
        float s = vv[i][0] + vv[i][1] + vv[i][2] + vv[i][3];
        #pragma unroll
        for (int o = 32; o > 0; o >>= 1) s += __shfl_down(s, o);
        if ((t & 63) == 0) { atomicAdd(&trow[r0 + i], s); wtot += s; }
    }
    if ((t & 63) == 0) ws[t >> 6] = wtot;
    // ---- col partial sums via LDS (4 row-groups share 256 tile-cols) ----
    int g = t >> 6;
    #pragma unroll
    for (int j = 0; j < 4; ++j)
        cs[g][(t & 63) * 4 + j] = vv[0][j] + vv[1][j] + vv[2][j] + vv[3][j];
    __syncthreads();
    float csum = cs[0][t] + cs[1][t] + cs[2][t] + cs[3][t];
    atomicAdd(&tcol[blockIdx.x * 256 + t], csum);
    if (t == 0) atomicAdd(&sc[5], (double)(ws[0] + ws[1] + ws[2] + ws[3]));
}

// ---------------- cosine-cost kernels ----------------
template <int SELF>
__global__ __launch_bounds__(256) void cost_kernel(
        const float* __restrict__ EA, const float* __restrict__ EB,
        const float* __restrict__ ea, const float* __restrict__ eb,
        const float* __restrict__ ref_or_trans,
        const float* __restrict__ mu, const float* __restrict__ tsum,
        unsigned short* __restrict__ outD, double* __restrict__ sc) {
    __shared__ float As[16][68];
    __shared__ float Bs[16][68];
    __shared__ double red[256];
    int t = threadIdx.x;
    int tx = t & 15, ty = t >> 4;
    int bi = blockIdx.y * 64, bj = blockIdx.x * 64;
    float acc[4][4] = {};
    for (int kk = 0; kk < D; kk += 16) {
        #pragma unroll
        for (int r = 0; r < 4; ++r) {
            int e = t + 256 * r;
            int ar = e >> 4, ac = e & 15;
            As[ac][ar] = EA[(size_t)(bi + ar) * D + kk + ac];
            Bs[ac][ar] = EB[(size_t)(bj + ar) * D + kk + ac];
        }
        __syncthreads();
        #pragma unroll
        for (int k = 0; k < 16; ++k) {
            float4 av = *(const float4*)&As[k][ty * 4];
            float4 bv = *(const float4*)&Bs[k][tx * 4];
            float a[4] = {av.x, av.y, av.z, av.w};
            float b[4] = {bv.x, bv.y, bv.z, bv.w};
            #pragma unroll
            for (int u = 0; u < 4; ++u)
                #pragma unroll
                for (int v = 0; v < 4; ++v)
                    acc[u][v] = fmaf(a[u], b[v], acc[u][v]);
        }
        __syncthreads();
    }
    float eav[4], ebv[4];
    #pragma unroll
    for (int u = 0; u < 4; ++u) eav[u] = ea[bi + ty * 4 + u];
    #pragma unroll
    for (int v = 0; v < 4; ++v) ebv[v] = eb[bj + tx * 4 + v];

    double l1 = 0.0, l2 = 0.0;
    #pragma unroll
    for (int u = 0; u < 4; ++u) {
        int ri = bi + ty * 4 + u;
        float cv[4];
        #pragma unroll
        for (int v = 0; v < 4; ++v) {
            int ci = bj + tx * 4 + v;
            size_t id = (size_t)ri * N + ci;
            float denom = eav[u] * ebv[v] + FEPS;
            float cosv = acc[u][v] / denom;
            if (SELF) {
                float c = 1.f - expf(-5.f * (1.f - cosv));
                cv[v] = c;
                float rc = ref_or_trans[id];
                float dd = c - rc;
                l1 += (double)(dd * dd * expf(-rc));
                l2 += (double)(c * c) * (double)mu[ci] * (double)tsum[ri];
            } else {
                float c = 1.f - expf(-(1.f - cosv));
                l1 += (double)c * (double)ref_or_trans[id];
            }
        }
        if (SELF) {
            int ci0 = bj + tx * 4;
            size_t slot = ((size_t)(ri >> 4) * (N / 8) + (ci0 >> 3)) * 128 + (ri & 15) * 8 + (ci0 & 7);
            short4 s;
            s.x = (short)f2bf(cv[0] - C0F); s.y = (short)f2bf(cv[1] - C0F);
            s.z = (short)f2bf(cv[2] - C0F); s.w = (short)f2bf(cv[3] - C0F);
            *(short4*)&outD[slot] = s;
        }
    }
    double s1 = block_reduce256(l1, red);
    if (SELF) {
        double s2v = block_reduce256(l2, red);
        if (t == 0) { atomicAdd(&sc[0], s1); atomicAdd(&sc[1], s2v); }
    } else {
        if (t == 0) atomicAdd(&sc[3], s1);
    }
}

// ---------------- bf16 MFMA GEMM, 128x128 tile, 1-barrier dbuf pipeline -----
__device__ __forceinline__ void mfma_step(const char* ard, const char* brd,
                                          f32x4 (&acc)[4][4]) {
    bf16x8 af[4], bfr[4];
    #pragma unroll
    for (int f = 0; f < 4; ++f) {
        af[f]  = *(const bf16x8*)(ard + f * 1024);
        bfr[f] = *(const bf16x8*)(brd + f * 1024);
    }
    #pragma unroll
    for (int mf = 0; mf < 4; ++mf)
        #pragma unroll
        for (int nf = 0; nf < 4; ++nf)
            acc[mf][nf] = __builtin_amdgcn_mfma_f32_16x16x32_bf16(
                af[mf], bfr[nf], acc[mf][nf], 0, 0, 0);
}

// STORE=1: Pd = A@B -> Pdb (bf16, C-fragment-native tiled layout)
// STORE=0: Qd = A@B; epilogue: sc[6]+=Σ tcol[j]*Qd, sc[7]+=Σ trow[i]*Pd,
//          sc[2]+=Σ Pd*Qd
template <int STORE>
__global__ __launch_bounds__(256, 3) void gemm_mfma(
        const unsigned short* __restrict__ Ag, const unsigned short* __restrict__ Bg,
        unsigned short* __restrict__ Pdb,
        const float* __restrict__ trow, const float* __restrict__ tcol,
        double* __restrict__ sc) {
    __shared__ __align__(16) char Abuf[2][8192];
    __shared__ __align__(16) char Bbuf[2][8192];
    __shared__ double red[256];
    const int t = threadIdx.x, l = t & 63;
    // wave id is wave-uniform: force into SGPR so all address bases scalarize
    const int w = __builtin_amdgcn_readfirstlane(t >> 6);
    const int wm = w >> 1, wn = w & 1;
    // XCD-aware swizzle: xcd = lid%8 owns a 4-row band, walks columns
    const int lid = blockIdx.x;
    const int by = (lid & 7) * 4 + ((lid >> 3) & 3);
    const int bx = lid >> 5;
    const size_t grp = (size_t)(N / 8) * 256;  // bytes per 16-row group (all k)

    const char* aG = (const char*)Ag + (size_t)(by * 8 + w * 2) * grp + (size_t)(l * 16);
    const char* bG = (const char*)Bg + (size_t)(bx * 8 + w * 2) * grp + (size_t)(l * 16);

    f32x4 acc[4][4];
    #pragma unroll
    for (int i = 0; i < 4; ++i)
        #pragma unroll
        for (int j = 0; j < 4; ++j)
            acc[i][j] = (f32x4){0.f, 0.f, 0.f, 0.f};

    // prologue: stage chunk 0 -> buf 0
    async16(&Abuf[0][w * 2048],        aG);
    async16(&Abuf[0][w * 2048 + 1024], aG + grp);
    async16(&Bbuf[0][w * 2048],        bG);
    async16(&Bbuf[0][w * 2048 + 1024], bG + grp);

    for (int it = 0; it < N / 32; ++it) {
        __syncthreads();  // drains chunk it staging; retires reads of buf it-1
        const int ph = it & 1, pn = ph ^ 1;
        if (it + 1 < N / 32) {
            const char* a = aG + (size_t)(it + 1) * 1024;
            const char* b = bG + (size_t)(it + 1) * 1024;
            async16(&Abuf[pn][w * 2048],        a);
            async16(&Abuf[pn][w * 2048 + 1024], a + grp);
            async16(&Bbuf[pn][w * 2048],        b);
            async16(&Bbuf[pn][w * 2048 + 1024], b + grp);
        }
        mfma_step(&Abuf[ph][wm * 4096] + l * 16, &Bbuf[ph][wn * 4096] + l * 16, acc);
    }

    const size_t blkbase = (size_t)(by * 32 + bx) * 4096 + (size_t)w * 1024;
    if (STORE) {
        #pragma unroll
        for (int mf = 0; mf < 4; ++mf)
            #pragma unroll
            for (int nf = 0; nf < 4; ++nf) {
                f32x4 a = acc[mf][nf];
                short4 s;
                s.x = (short)f2bf(a[0]); s.y = (short)f2bf(a[1]);
                s.z = (short)f2bf(a[2]); s.w = (short)f2bf(a[3]);
                *(short4*)&Pdb[(blkbase + (mf * 4 + nf) * 64 + l) * 4] = s;
            }
    } else {
        double t1 = 0.0, t2 = 0.0, t3 = 0.0;
        const int quad = l >> 4, lan = l & 15;
        #pragma unroll
        for (int mf = 0; mf < 4; ++mf) {
            const int ib = by * 128 + wm * 64 + mf * 16 + quad * 4;  // row i base
            float4 tr4 = *(const float4*)&trow[ib];
            float trv[4] = {tr4.x, tr4.y, tr4.z, tr4.w};
            #pragma unroll
            for (int nf = 0; nf < 4; ++nf) {
                const int j = bx * 128 + wn * 64 + nf * 16 + lan;    // col j
                const float tcj = tcol[j];
                short4 p = *(const short4*)&Pdb[(blkbase + (mf * 4 + nf) * 64 + l) * 4];
                float pf[4] = {bf2f(p.x), bf2f(p.y), bf2f(p.z), bf2f(p.w)};
                #pragma unroll
                for (int r = 0; r < 4; ++r) {
                    double x = (double)acc[mf][nf][r];
                    t1 += (double)tcj * x;
                    t2 += (double)trv[r] * (double)pf[r];
                    t3 += x * (double)pf[r];
                }
            }
        }
        double s1 = block_reduce256(t1, red);
        double s2 = block_reduce256(t2, red);
        double s3 = block_reduce256(t3, red);
        if (t == 0) {
            atomicAdd(&sc[6], s1);
            atomicAdd(&sc[7], s2);
            atomicAdd(&sc[2], s3);
        }
    }
}

// ---------------- orthogonality: tiled gram partials + finalize -------------
__global__ __launch_bounds__(256) void gram_partial(const float* __restrict__ E,
                                                    float* __restrict__ G) {
    __shared__ float Es[16][132];
    int t = threadIdx.x, tx = t & 15, ty = t >> 4;
    int i0 = blockIdx.x * 128;
    float acc[8][8] = {};
    for (int kk = 0; kk < 128; kk += 16) {
        #pragma unroll
        for (int r = 0; r < 2; ++r) {
            int q = t + 256 * r;
            int row = q >> 5, c4 = (q & 31) * 4;
            *(float4*)&Es[row][c4] = *(const float4*)&E[(size_t)(i0 + kk + row) * D + c4];
        }
        __syncthreads();
        #pragma unroll
        for (int k = 0; k < 16; ++k) {
            float a[8], b[8];
            *(float4*)&a[0] = *(const float4*)&Es[k][ty * 8];
            *(float4*)&a[4] = *(const float4*)&Es[k][ty * 8 + 4];
            *(float4*)&b[0] = *(const float4*)&Es[k][tx * 8];
            *(float4*)&b[4] = *(const float4*)&Es[k][tx * 8 + 4];
            #pragma unroll
            for (int u = 0; u < 8; ++u)
                #pragma unroll
                for (int v = 0; v < 8; ++v)
                    acc[u][v] = fmaf(a[u], b[v], acc[u][v]);
        }
        __syncthreads();
    }
    #pragma unroll
    for (int u = 0; u < 8; ++u)
        #pragma unroll
        for (int v = 0; v < 8; ++v)
            atomicAdd(&G[(size_t)(ty * 8 + u) * D + tx * 8 + v], acc[u][v]);
}

__global__ void orth_final(const float* __restrict__ G, double* __restrict__ sc) {
    __shared__ double red[256];
    const float* g = G + (size_t)blockIdx.x * D * D;
    int t = threadIdx.x;
    double s = 0.0;
    for (int q = t; q < D * D; q += 256) {
        float v = g[q] - ((q % (D + 1)) == 0 ? 1.f : 0.f);
        s += (double)v * (double)v;
    }
    double r = block_reduce256(s, red);
    if (t == 0) atomicAdd(&sc[4], r);
}

// ---------------- finalize ----------------
__global__ void finalize(const double* __restrict__ sc, float* __restrict__ out) {
    if (threadIdx.x == 0) {
        const double C0 = (double)C0F;
        double S = sc[5];
        double pq = C0 * C0 * S * S + C0 * sc[6] + C0 * sc[7] + sc[2];
        out[0] = (float)(sc[1] - 2.0 * pq);  // d_gw
        out[1] = (float)sc[3];               // d_w
        out[2] = (float)(sc[0] + sc[4]);     // regularizer
    }
}

extern "C" void kernel_launch(void* const* d_in, const int* in_sizes, int n_in,
                              void* d_out, int out_size, void* d_ws, size_t ws_size,
                              hipStream_t stream) {
    const int*   index1 = (const int*)d_in[0];
    const int*   index2 = (const int*)d_in[1];
    const float* trans  = (const float*)d_in[2];
    const float* mu_s   = (const float*)d_in[3];
    const float* mu_t   = (const float*)d_in[4];
    const float* cost1  = (const float*)d_in[5];
    const float* cost2  = (const float*)d_in[6];
    const float* emb1_w = (const float*)d_in[7];
    const float* emb2_w = (const float*)d_in[8];
    float* out = (float*)d_out;

    char* w = (char*)d_ws;
    double* sc  = (double*)w;                          // 8 doubles @0
    float* tcol = (float*)(w + 256);                   // 16 KB (zeroed)
    float* trow = (float*)(w + 16640);                 // 16 KB (zeroed - atomics)
    float* e1   = (float*)(w + 33024);                 // 16 KB
    float* e2   = (float*)(w + 49408);                 // 16 KB
    float* E1   = (float*)(w + 65792);                 // 2 MB
    float* E2   = (float*)(w + 2162944);               // 2 MB
    unsigned short* Ds  = (unsigned short*)(w + 4260096);    // 32 MB (Δs, then Δt)
    unsigned short* Ta  = (unsigned short*)(w + 37814528);   // 32 MB trans A-fmt
    unsigned short* Tb  = (unsigned short*)(w + 71368960);   // 32 MB trans B-fmt
    unsigned short* Pdb = (unsigned short*)(w + 104923392);  // 32 MB Pd bf16 (C-layout)
    float* Gbuf = (float*)(w + 37814528);              // 128 KB, overlays Ta (dead after gemm2)

    hipMemsetAsync(d_ws, 0, 33024, stream);  // sc + tcol + trow

    gather_energy<<<N, D, 0, stream>>>(emb1_w, index1, E1, e1);
    gather_energy<<<N, D, 0, stream>>>(emb2_w, index2, E2, e2);
    // single pass over trans: bf16 convert (A+B fmt) + row/col sums + total
    trans_convert<<<dim3(16, 256), 256, 0, stream>>>(trans, Ta, Tb, trow, tcol, sc);

    dim3 g64(N / 64, N / 64);

    // Δs (+ sim1 -> sc[0], f1-term -> sc[1])
    cost_kernel<1><<<g64, 256, 0, stream>>>(E1, E1, e1, e1, cost1, mu_s, trow, Ds, sc);
    // Pd = Δs @ trans
    gemm_mfma<1><<<1024, 256, 0, stream>>>(Ds, Tb, Pdb, nullptr, nullptr, sc);
    // Δt (+ sim2 -> sc[0], f2-term -> sc[1]); reuses Ds
    cost_kernel<1><<<g64, 256, 0, stream>>>(E2, E2, e2, e2, cost2, mu_t, tcol, Ds, sc);
    // Qd = trans @ Δt; fused epilogue (sc[2], sc[6], sc[7])
    gemm_mfma<0><<<1024, 256, 0, stream>>>(Ta, Ds, Pdb, trow, tcol, sc);
    // d_w -> sc[3]
    cost_kernel<0><<<g64, 256, 0, stream>>>(E1, E2, e1, e2, trans, nullptr, nullptr, nullptr, sc);
    // orthogonality
    hipMemsetAsync(Gbuf, 0, 2 * D * D * sizeof(float), stream);
    gram_partial<<<32, 256, 0, stream>>>(E1, Gbuf);
    gram_partial<<<32, 256, 0, stream>>>(E2, Gbuf + D * D);
    orth_final<<<2, 256, 0, stream>>>(Gbuf, sc);

    finalize<<<1, 64, 0, stream>>>(sc, out);
}

// Round 3
// 954.943 us; speedup vs baseline: 1.0719x; 1.0719x over previous
//
#include <hip/hip_runtime.h>
#include <math.h>

#define N 4096
#define D 128
#define FEPS 1e-5f
#define C0F 0.993262053f
#define NT 64  // K-tiles of 64 (4096/64)

typedef __attribute__((ext_vector_type(8))) short bf16x8;
typedef __attribute__((ext_vector_type(4))) float f32x4;

__device__ __forceinline__ unsigned short f2bf(float f) {
    union { float f; unsigned u; } v; v.f = f;
    unsigned r = v.u + 0x7fffu + ((v.u >> 16) & 1u);
    return (unsigned short)(r >> 16);
}
__device__ __forceinline__ float bf2f(short s) {
    union { unsigned u; float f; } v; v.u = ((unsigned)(unsigned short)s) << 16;
    return v.f;
}

__device__ __forceinline__ void async16(void* lds, const void* g) {
    __builtin_amdgcn_global_load_lds(
        (const __attribute__((address_space(1))) unsigned int*)g,
        (__attribute__((address_space(3))) unsigned int*)lds, 16, 0, 0);
}

// ---------------- reduction helpers ----------------
__device__ __forceinline__ double block_reduce256(double v, double* red) {
    int t = threadIdx.x;
    red[t] = v;
    __syncthreads();
    #pragma unroll
    for (int s = 128; s > 0; s >>= 1) {
        if (t < s) red[t] += red[t + s];
        __syncthreads();
    }
    double r = red[0];
    __syncthreads();
    return r;
}

__device__ __forceinline__ double block_reduce512(double v, double* red) {
    int t = threadIdx.x;
    red[t] = v;
    __syncthreads();
    #pragma unroll
    for (int s = 256; s > 0; s >>= 1) {
        if (t < s) red[t] += red[t + s];
        __syncthreads();
    }
    double r = red[0];
    __syncthreads();
    return r;
}

// ---------------- gather + row norms ----------------
__global__ void gather_energy(const float* __restrict__ W, const int* __restrict__ idx,
                              float* __restrict__ E, float* __restrict__ energy) {
    int i = blockIdx.x, t = threadIdx.x;
    float v = W[(size_t)idx[i] * D + t];
    E[(size_t)i * D + t] = v;
    float sq = v * v;
    #pragma unroll
    for (int o = 32; o > 0; o >>= 1) sq += __shfl_down(sq, o);
    __shared__ float s2[2];
    if ((t & 63) == 0) s2[t >> 6] = sq;
    __syncthreads();
    if (t == 0) energy[i] = sqrtf(s2[0] + s2[1]);
}

// ---------------- trans -> bf16 A-fmt (Ta) + B-fmt (Tb), FUSED row/col sums --
// A-fmt slot(r,c) = ((r>>4)*(N/8) + (c>>3))*128 + (r&15)*8 + (c&7), holds M[r][c]
// B-fmt slot for (k,n) = A-fmt slot(n,k), holds M[k][n]
// Also: trow[i] += row sums, tcol[j] += col sums, sc[5] += total (one 64MB pass
// instead of three).  trow/tcol must be zeroed.
__global__ void trans_convert(const float* __restrict__ T,
                              unsigned short* __restrict__ Ta,
                              unsigned short* __restrict__ Tb,
                              float* __restrict__ trow, float* __restrict__ tcol,
                              double* __restrict__ sc) {
    __shared__ float cs[4][256];
    __shared__ float ws[4];
    int t = threadIdx.x;
    int cb = blockIdx.x * 64 + (t & 63);   // col-block (4 cols)
    int rb = blockIdx.y * 4 + (t >> 6);    // row-block (4 rows)
    int r0 = rb * 4, c0 = cb * 4;
    float vv[4][4];
    #pragma unroll
    for (int i = 0; i < 4; ++i) {
        float4 r4 = *(const float4*)&T[(size_t)(r0 + i) * N + c0];
        vv[i][0] = r4.x; vv[i][1] = r4.y; vv[i][2] = r4.z; vv[i][3] = r4.w;
    }
    #pragma unroll
    for (int i = 0; i < 4; ++i) {
        int r = r0 + i;
        size_t slot = ((size_t)(r >> 4) * (N / 8) + (c0 >> 3)) * 128 + (r & 15) * 8 + (c0 & 7);
        short4 s;
        s.x = (short)f2bf(vv[i][0]); s.y = (short)f2bf(vv[i][1]);
        s.z = (short)f2bf(vv[i][2]); s.w = (short)f2bf(vv[i][3]);
        *(short4*)&Ta[slot] = s;
    }
    #pragma unroll
    for (int j = 0; j < 4; ++j) {
        int n = c0 + j;
        size_t slot = ((size_t)(n >> 4) * (N / 8) + (r0 >> 3)) * 128 + (n & 15) * 8 + (r0 & 7);
        short4 s;
        s.x = (short)f2bf(vv[0][j]); s.y = (short)f2bf(vv[1][j]);
        s.z = (short)f2bf(vv[2][j]); s.w = (short)f2bf(vv[3][j]);
        *(short4*)&Tb[slot] = s;
    }
    // ---- row sums: the 64 lanes of a wave all own the same 4 rows ----
    float wtot = 0.f;
    #pragma unroll
    for (int i = 0; i < 4; ++i) {
        float s = vv[i][0] + vv[i][1] + vv[i][2] + vv[i][3];
        #pragma unroll
        for (int o = 32; o > 0; o >>= 1) s += __shfl_down(s, o);
        if ((t & 63) == 0) { atomicAdd(&trow[r0 + i], s); wtot += s; }
    }
    if ((t & 63) == 0) ws[t >> 6] = wtot;
    // ---- col partial sums via LDS (4 row-groups share 256 tile-cols) ----
    int g = t >> 6;
    #pragma unroll
    for (int j = 0; j < 4; ++j)
        cs[g][(t & 63) * 4 + j] = vv[0][j] + vv[1][j] + vv[2][j] + vv[3][j];
    __syncthreads();
    float csum = cs[0][t] + cs[1][t] + cs[2][t] + cs[3][t];
    atomicAdd(&tcol[blockIdx.x * 256 + t], csum);
    if (t == 0) atomicAdd(&sc[5], (double)(ws[0] + ws[1] + ws[2] + ws[3]));
}

// ---------------- cosine-cost kernels ----------------
template <int SELF>
__global__ __launch_bounds__(256) void cost_kernel(
        const float* __restrict__ EA, const float* __restrict__ EB,
        const float* __restrict__ ea, const float* __restrict__ eb,
        const float* __restrict__ ref_or_trans,
        const float* __restrict__ mu, const float* __restrict__ tsum,
        unsigned short* __restrict__ outD, double* __restrict__ sc) {
    __shared__ float As[16][68];
    __shared__ float Bs[16][68];
    __shared__ double red[256];
    int t = threadIdx.x;
    int tx = t & 15, ty = t >> 4;
    int bi = blockIdx.y * 64, bj = blockIdx.x * 64;
    float acc[4][4] = {};
    for (int kk = 0; kk < D; kk += 16) {
        #pragma unroll
        for (int r = 0; r < 4; ++r) {
            int e = t + 256 * r;
            int ar = e >> 4, ac = e & 15;
            As[ac][ar] = EA[(size_t)(bi + ar) * D + kk + ac];
            Bs[ac][ar] = EB[(size_t)(bj + ar) * D + kk + ac];
        }
        __syncthreads();
        #pragma unroll
        for (int k = 0; k < 16; ++k) {
            float4 av = *(const float4*)&As[k][ty * 4];
            float4 bv = *(const float4*)&Bs[k][tx * 4];
            float a[4] = {av.x, av.y, av.z, av.w};
            float b[4] = {bv.x, bv.y, bv.z, bv.w};
            #pragma unroll
            for (int u = 0; u < 4; ++u)
                #pragma unroll
                for (int v = 0; v < 4; ++v)
                    acc[u][v] = fmaf(a[u], b[v], acc[u][v]);
        }
        __syncthreads();
    }
    float eav[4], ebv[4];
    #pragma unroll
    for (int u = 0; u < 4; ++u) eav[u] = ea[bi + ty * 4 + u];
    #pragma unroll
    for (int v = 0; v < 4; ++v) ebv[v] = eb[bj + tx * 4 + v];

    double l1 = 0.0, l2 = 0.0;
    #pragma unroll
    for (int u = 0; u < 4; ++u) {
        int ri = bi + ty * 4 + u;
        float cv[4];
        #pragma unroll
        for (int v = 0; v < 4; ++v) {
            int ci = bj + tx * 4 + v;
            size_t id = (size_t)ri * N + ci;
            float denom = eav[u] * ebv[v] + FEPS;
            float cosv = acc[u][v] / denom;
            if (SELF) {
                float c = 1.f - expf(-5.f * (1.f - cosv));
                cv[v] = c;
                float rc = ref_or_trans[id];
                float dd = c - rc;
                l1 += (double)(dd * dd * expf(-rc));
                l2 += (double)(c * c) * (double)mu[ci] * (double)tsum[ri];
            } else {
                float c = 1.f - expf(-(1.f - cosv));
                l1 += (double)c * (double)ref_or_trans[id];
            }
        }
        if (SELF) {
            int ci0 = bj + tx * 4;
            size_t slot = ((size_t)(ri >> 4) * (N / 8) + (ci0 >> 3)) * 128 + (ri & 15) * 8 + (ci0 & 7);
            short4 s;
            s.x = (short)f2bf(cv[0] - C0F); s.y = (short)f2bf(cv[1] - C0F);
            s.z = (short)f2bf(cv[2] - C0F); s.w = (short)f2bf(cv[3] - C0F);
            *(short4*)&outD[slot] = s;
        }
    }
    double s1 = block_reduce256(l1, red);
    if (SELF) {
        double s2v = block_reduce256(l2, red);
        if (t == 0) { atomicAdd(&sc[0], s1); atomicAdd(&sc[1], s2v); }
    } else {
        if (t == 0) atomicAdd(&sc[3], s1);
    }
}

// ---------------- bf16 MFMA GEMM, 256x256 tile, counted-vmcnt 4-phase -------
// 8 waves (2M x 4N), BK=64 split in two k-halves; per phase: ds-read subtile,
// issue 1 half-tile (2 x global_load_lds), 16 MFMA, [vmcnt(6) at phases 1,3],
// one raw s_barrier.  Loads stay in flight across barriers (never vmcnt(0)
// in steady state).  LDS ring: buf[2] x {A,B} x {kh0,kh1} x 16KB = 128KB.
#define MFMA16(a, b, c) __builtin_amdgcn_mfma_f32_16x16x32_bf16(a, b, c, 0, 0, 0)

// STORE=1: Pd = A@B -> Pdb (bf16, C-fragment-native tiled layout)
// STORE=0: Qd = A@B; epilogue: sc[6]+=Σ tcol[j]*Qd, sc[7]+=Σ trow[i]*Pd,
//          sc[2]+=Σ Pd*Qd
template <int STORE>
__global__ __launch_bounds__(512, 2) void gemm_mfma(
        const unsigned short* __restrict__ Ag, const unsigned short* __restrict__ Bg,
        unsigned short* __restrict__ Pdb,
        const float* __restrict__ trow, const float* __restrict__ tcol,
        double* __restrict__ sc) {
    __shared__ __align__(16) char Lds[131072];
    __shared__ double red[512];
    const int t = threadIdx.x, l = t & 63;
    const int w = __builtin_amdgcn_readfirstlane(t >> 6);
    const int wm = w >> 2, wn = w & 3;
    // XCD-aware swizzle: 256 blocks, nwg%8==0 -> bijective chunked map
    const int lid = blockIdx.x;
    const int swz = (lid & 7) * 32 + (lid >> 3);
    const int by = swz >> 4, bx = swz & 15;
    const size_t GRP = (size_t)(N / 8) * 256;  // 131072 B per 16-row group (all k)

    // staging sources: group = tile*16 + q*8 + w, k-slice tt*2048 + kh*1024
    const char* aBase = (const char*)Ag + ((size_t)by * 16 + w) * GRP + (size_t)l * 16;
    const char* bBase = (const char*)Bg + ((size_t)bx * 16 + w) * GRP + (size_t)l * 16;

#define ISSUE_A(KH, TT) do {                                                   \
    char* _d = Lds + ((TT) & 1) * 65536 + (KH) * 16384 + w * 1024;             \
    const char* _g = aBase + (size_t)(TT) * 2048 + (KH) * 1024;                \
    async16(_d, _g); async16(_d + 8192, _g + 8 * GRP); } while (0)
#define ISSUE_B(KH, TT) do {                                                   \
    char* _d = Lds + ((TT) & 1) * 65536 + 32768 + (KH) * 16384 + w * 1024;     \
    const char* _g = bBase + (size_t)(TT) * 2048 + (KH) * 1024;                \
    async16(_d, _g); async16(_d + 8192, _g + 8 * GRP); } while (0)

    f32x4 acc[8][4];
    #pragma unroll
    for (int i = 0; i < 8; ++i)
        #pragma unroll
        for (int j = 0; j < 4; ++j)
            acc[i][j] = (f32x4){0.f, 0.f, 0.f, 0.f};

    // prologue: pre-issue A0(0), B0(0), A1(0), B1(0), A0(1); drain oldest 2
    ISSUE_A(0, 0); ISSUE_B(0, 0); ISSUE_A(1, 0); ISSUE_B(1, 0); ISSUE_A(0, 1);
    asm volatile("s_waitcnt vmcnt(6)" ::: "memory");
    __builtin_amdgcn_s_barrier();
    asm volatile("" ::: "memory");

    bf16x8 af[8];
    const char* Albase = Lds + wm * 8192;            // + bufo + ks*16384 + mf*1024 + l*16
    const char* Blbase = Lds + 32768 + wn * 4096;    // + bufo + ks*16384 + nf*1024 + l*16

    for (int tt = 0; tt < NT; ++tt) {
        const int bufo = (tt & 1) * 65536;
        // ---- phase 0: ks=0, nf 0..1; issue B-kh0(tt+1) ----
        {
            const char* Ab = Albase + bufo;
            const char* Bb = Blbase + bufo;
            #pragma unroll
            for (int mf = 0; mf < 8; ++mf)
                af[mf] = *(const bf16x8*)(Ab + mf * 1024 + l * 16);
            bf16x8 b0 = *(const bf16x8*)(Bb + l * 16);
            bf16x8 b1 = *(const bf16x8*)(Bb + 1024 + l * 16);
            if (tt + 1 < NT) ISSUE_B(0, tt + 1);
            __builtin_amdgcn_s_setprio(1);
            #pragma unroll
            for (int mf = 0; mf < 8; ++mf) {
                acc[mf][0] = MFMA16(af[mf], b0, acc[mf][0]);
                acc[mf][1] = MFMA16(af[mf], b1, acc[mf][1]);
            }
            __builtin_amdgcn_s_setprio(0);
            asm volatile("" ::: "memory");
            __builtin_amdgcn_s_barrier();
            asm volatile("" ::: "memory");
        }
        // ---- phase 1: ks=0, nf 2..3; issue A-kh1(tt+1); vmcnt ----
        {
            const char* Bb = Blbase + bufo + 2048;
            bf16x8 b0 = *(const bf16x8*)(Bb + l * 16);
            bf16x8 b1 = *(const bf16x8*)(Bb + 1024 + l * 16);
            if (tt + 1 < NT) ISSUE_A(1, tt + 1);
            __builtin_amdgcn_s_setprio(1);
            #pragma unroll
            for (int mf = 0; mf < 8; ++mf) {
                acc[mf][2] = MFMA16(af[mf], b0, acc[mf][2]);
                acc[mf][3] = MFMA16(af[mf], b1, acc[mf][3]);
            }
            __builtin_amdgcn_s_setprio(0);
            if (tt < NT - 1) { asm volatile("s_waitcnt vmcnt(6)" ::: "memory"); }
            else             { asm volatile("s_waitcnt vmcnt(0)" ::: "memory"); }
            asm volatile("" ::: "memory");
            __builtin_amdgcn_s_barrier();
            asm volatile("" ::: "memory");
        }
        // ---- phase 2: ks=1, nf 0..1; issue B-kh1(tt+1) ----
        {
            const char* Ab = Albase + bufo + 16384;
            const char* Bb = Blbase + bufo + 16384;
            #pragma unroll
            for (int mf = 0; mf < 8; ++mf)
                af[mf] = *(const bf16x8*)(Ab + mf * 1024 + l * 16);
            bf16x8 b0 = *(const bf16x8*)(Bb + l * 16);
            bf16x8 b1 = *(const bf16x8*)(Bb + 1024 + l * 16);
            if (tt + 1 < NT) ISSUE_B(1, tt + 1);
            __builtin_amdgcn_s_setprio(1);
            #pragma unroll
            for (int mf = 0; mf < 8; ++mf) {
                acc[mf][0] = MFMA16(af[mf], b0, acc[mf][0]);
                acc[mf][1] = MFMA16(af[mf], b1, acc[mf][1]);
            }
            __builtin_amdgcn_s_setprio(0);
            asm volatile("" ::: "memory");
            __builtin_amdgcn_s_barrier();
            asm volatile("" ::: "memory");
        }
        // ---- phase 3: ks=1, nf 2..3; issue A-kh0(tt+2); vmcnt ----
        {
            const char* Bb = Blbase + bufo + 16384 + 2048;
            bf16x8 b0 = *(const bf16x8*)(Bb + l * 16);
            bf16x8 b1 = *(const bf16x8*)(Bb + 1024 + l * 16);
            if (tt + 2 < NT) ISSUE_A(0, tt + 2);
            __builtin_amdgcn_s_setprio(1);
            #pragma unroll
            for (int mf = 0; mf < 8; ++mf) {
                acc[mf][2] = MFMA16(af[mf], b0, acc[mf][2]);
                acc[mf][3] = MFMA16(af[mf], b1, acc[mf][3]);
            }
            __builtin_amdgcn_s_setprio(0);
            if (tt < NT - 2)       { asm volatile("s_waitcnt vmcnt(6)" ::: "memory"); }
            else if (tt == NT - 2) { asm volatile("s_waitcnt vmcnt(4)" ::: "memory"); }
            asm volatile("" ::: "memory");
            __builtin_amdgcn_s_barrier();
            asm volatile("" ::: "memory");
        }
    }
#undef ISSUE_A
#undef ISSUE_B

    const size_t base = ((size_t)(by * 16 + bx)) * 65536 + (size_t)w * 8192;
    if (STORE) {
        #pragma unroll
        for (int mf = 0; mf < 8; ++mf)
            #pragma unroll
            for (int nf = 0; nf < 4; ++nf) {
                f32x4 a = acc[mf][nf];
                short4 s;
                s.x = (short)f2bf(a[0]); s.y = (short)f2bf(a[1]);
                s.z = (short)f2bf(a[2]); s.w = (short)f2bf(a[3]);
                *(short4*)&Pdb[base + (size_t)(mf * 4 + nf) * 256 + (size_t)l * 4] = s;
            }
    } else {
        double t1 = 0.0, t2 = 0.0, t3 = 0.0;
        const int quad = l >> 4, lan = l & 15;
        #pragma unroll
        for (int mf = 0; mf < 8; ++mf) {
            const int ib = by * 256 + wm * 128 + mf * 16 + quad * 4;  // row i base
            float4 tr4 = *(const float4*)&trow[ib];
            float trv[4] = {tr4.x, tr4.y, tr4.z, tr4.w};
            #pragma unroll
            for (int nf = 0; nf < 4; ++nf) {
                const int j = bx * 256 + wn * 64 + nf * 16 + lan;    // col j
                const float tcj = tcol[j];
                short4 p = *(const short4*)&Pdb[base + (size_t)(mf * 4 + nf) * 256 + (size_t)l * 4];
                float pf[4] = {bf2f(p.x), bf2f(p.y), bf2f(p.z), bf2f(p.w)};
                #pragma unroll
                for (int r = 0; r < 4; ++r) {
                    double x = (double)acc[mf][nf][r];
                    t1 += (double)tcj * x;
                    t2 += (double)trv[r] * (double)pf[r];
                    t3 += x * (double)pf[r];
                }
            }
        }
        double s1 = block_reduce512(t1, red);
        double s2 = block_reduce512(t2, red);
        double s3 = block_reduce512(t3, red);
        if (t == 0) {
            atomicAdd(&sc[6], s1);
            atomicAdd(&sc[7], s2);
            atomicAdd(&sc[2], s3);
        }
    }
}

// ---------------- orthogonality: tiled gram partials + finalize -------------
__global__ __launch_bounds__(256) void gram_partial(const float* __restrict__ E,
                                                    float* __restrict__ G) {
    __shared__ float Es[16][132];
    int t = threadIdx.x, tx = t & 15, ty = t >> 4;
    int i0 = blockIdx.x * 128;
    float acc[8][8] = {};
    for (int kk = 0; kk < 128; kk += 16) {
        #pragma unroll
        for (int r = 0; r < 2; ++r) {
            int q = t + 256 * r;
            int row = q >> 5, c4 = (q & 31) * 4;
            *(float4*)&Es[row][c4] = *(const float4*)&E[(size_t)(i0 + kk + row) * D + c4];
        }
        __syncthreads();
        #pragma unroll
        for (int k = 0; k < 16; ++k) {
            float a[8], b[8];
            *(float4*)&a[0] = *(const float4*)&Es[k][ty * 8];
            *(float4*)&a[4] = *(const float4*)&Es[k][ty * 8 + 4];
            *(float4*)&b[0] = *(const float4*)&Es[k][tx * 8];
            *(float4*)&b[4] = *(const float4*)&Es[k][tx * 8 + 4];
            #pragma unroll
            for (int u = 0; u < 8; ++u)
                #pragma unroll
                for (int v = 0; v < 8; ++v)
                    acc[u][v] = fmaf(a[u], b[v], acc[u][v]);
        }
        __syncthreads();
    }
    #pragma unroll
    for (int u = 0; u < 8; ++u)
        #pragma unroll
        for (int v = 0; v < 8; ++v)
            atomicAdd(&G[(size_t)(ty * 8 + u) * D + tx * 8 + v], acc[u][v]);
}

__global__ void orth_final(const float* __restrict__ G, double* __restrict__ sc) {
    __shared__ double red[256];
    const float* g = G + (size_t)blockIdx.x * D * D;
    int t = threadIdx.x;
    double s = 0.0;
    for (int q = t; q < D * D; q += 256) {
        float v = g[q] - ((q % (D + 1)) == 0 ? 1.f : 0.f);
        s += (double)v * (double)v;
    }
    double r = block_reduce256(s, red);
    if (t == 0) atomicAdd(&sc[4], r);
}

// ---------------- finalize ----------------
__global__ void finalize(const double* __restrict__ sc, float* __restrict__ out) {
    if (threadIdx.x == 0) {
        const double C0 = (double)C0F;
        double S = sc[5];
        double pq = C0 * C0 * S * S + C0 * sc[6] + C0 * sc[7] + sc[2];
        out[0] = (float)(sc[1] - 2.0 * pq);  // d_gw
        out[1] = (float)sc[3];               // d_w
        out[2] = (float)(sc[0] + sc[4]);     // regularizer
    }
}

extern "C" void kernel_launch(void* const* d_in, const int* in_sizes, int n_in,
                              void* d_out, int out_size, void* d_ws, size_t ws_size,
                              hipStream_t stream) {
    const int*   index1 = (const int*)d_in[0];
    const int*   index2 = (const int*)d_in[1];
    const float* trans  = (const float*)d_in[2];
    const float* mu_s   = (const float*)d_in[3];
    const float* mu_t   = (const float*)d_in[4];
    const float* cost1  = (const float*)d_in[5];
    const float* cost2  = (const float*)d_in[6];
    const float* emb1_w = (const float*)d_in[7];
    const float* emb2_w = (const float*)d_in[8];
    float* out = (float*)d_out;

    char* w = (char*)d_ws;
    double* sc  = (double*)w;                          // 8 doubles @0
    float* tcol = (float*)(w + 256);                   // 16 KB (zeroed)
    float* trow = (float*)(w + 16640);                 // 16 KB (zeroed - atomics)
    float* e1   = (float*)(w + 33024);                 // 16 KB
    float* e2   = (float*)(w + 49408);                 // 16 KB
    float* E1   = (float*)(w + 65792);                 // 2 MB
    float* E2   = (float*)(w + 2162944);               // 2 MB
    unsigned short* Ds  = (unsigned short*)(w + 4260096);    // 32 MB (Δs, then Δt)
    unsigned short* Ta  = (unsigned short*)(w + 37814528);   // 32 MB trans A-fmt
    unsigned short* Tb  = (unsigned short*)(w + 71368960);   // 32 MB trans B-fmt
    unsigned short* Pdb = (unsigned short*)(w + 104923392);  // 32 MB Pd bf16 (C-layout)
    float* Gbuf = (float*)(w + 37814528);              // 128 KB, overlays Ta (dead after gemm2)

    hipMemsetAsync(d_ws, 0, 33024, stream);  // sc + tcol + trow

    gather_energy<<<N, D, 0, stream>>>(emb1_w, index1, E1, e1);
    gather_energy<<<N, D, 0, stream>>>(emb2_w, index2, E2, e2);
    // single pass over trans: bf16 convert (A+B fmt) + row/col sums + total
    trans_convert<<<dim3(16, 256), 256, 0, stream>>>(trans, Ta, Tb, trow, tcol, sc);

    dim3 g64(N / 64, N / 64);

    // Δs (+ sim1 -> sc[0], f1-term -> sc[1])
    cost_kernel<1><<<g64, 256, 0, stream>>>(E1, E1, e1, e1, cost1, mu_s, trow, Ds, sc);
    // Pd = Δs @ trans
    gemm_mfma<1><<<256, 512, 0, stream>>>(Ds, Tb, Pdb, nullptr, nullptr, sc);
    // Δt (+ sim2 -> sc[0], f2-term -> sc[1]); reuses Ds
    cost_kernel<1><<<g64, 256, 0, stream>>>(E2, E2, e2, e2, cost2, mu_t, tcol, Ds, sc);
    // Qd = trans @ Δt; fused epilogue (sc[2], sc[6], sc[7])
    gemm_mfma<0><<<256, 512, 0, stream>>>(Ta, Ds, Pdb, trow, tcol, sc);
    // d_w -> sc[3]
    cost_kernel<0><<<g64, 256, 0, stream>>>(E1, E2, e1, e2, trans, nullptr, nullptr, nullptr, sc);
    // orthogonality
    hipMemsetAsync(Gbuf, 0, 2 * D * D * sizeof(float), stream);
    gram_partial<<<32, 256, 0, stream>>>(E1, Gbuf);
    gram_partial<<<32, 256, 0, stream>>>(E2, Gbuf + D * D);
    orth_final<<<2, 256, 0, stream>>>(Gbuf, sc);

    finalize<<<1, 64, 0, stream>>>(sc, out);
}